// Round 4
// baseline (280.190 us; speedup 1.0000x reference)
//
#include <hip/hip_runtime.h>
#include <cmath>

// GaussCRF on MI355X — round 11.
// B=2, C=21, H=W=512, blur=4 -> h=w=128, K=11 (121 shifts), 5 iterations.
//
// r10 post-mortem: 271 us total; msg_k ~34 us x5 = 63% of runtime vs a
// 7.3 us LDS floor. Bottleneck theory: per-tap GLOBAL g loads sit on the
// dependent chain (load gv -> 6x ds_read_b128 -> 21 FMA) with only 2
// waves/SIMD of TLP -> exposed HBM latency every di-row.
// r11: msg_k only. Prefetch each wave's 33 g values into registers BEFORE
// the halo-staging loop (latency hides under staging + barrier); compute
// loop is then pure LDS+FMA. Wave 3 duplicates row 10 with a x0 mask
// (fmaf(0,q,acc) exact) so all waves run the same unrolled 3x11 shape.
// Numerics bit-identical to r10 (same tap order per wave, same reduce).

#define BB 2
#define CC 21
#define HH 512
#define WW 512
#define HP 128
#define WP 128
#define KF 11
#define SPAN 5
#define NB 121
#define NITER 5
#define PLF (HH*WW)
#define PLP (HP*WP)
#define PC 24      // packed channel stride (floats), 96 B = 6 x float4
#define LSTR 28    // halo LDS stride in floats (balanced: 8 lanes/bank-quad)
#define RSTR 25    // reduce-buffer lane stride (odd -> conflict-free)

__global__ void pool_img_k(const float* __restrict__ img,
                           const float* __restrict__ col_schan,
                           float* __restrict__ cf) {
    int idx = blockIdx.x * blockDim.x + threadIdx.x;
    if (idx >= BB*3*PLP) return;
    int Y  = idx & (WP-1);
    int X  = (idx >> 7) & (HP-1);
    int bc = idx >> 14;
    const float* base = img + ((size_t)bc*HH + X*4)*WW + Y*4;
    float s = 0.f;
    #pragma unroll
    for (int i = 0; i < 4; ++i)
        #pragma unroll
        for (int j = 0; j < 4; ++j)
            s += base[i*WW + j];
    cf[idx] = s * (1.f/16.f) * col_schan[0];
}

// g block-tiled: g[((b*16+tX)*16+tY)*121*64 + ij*64 + pos], pos = 8x8 tile.
__global__ void gauss_k(const float* __restrict__ cf,
                        const float* __restrict__ pos_sdims,
                        const float* __restrict__ pos_compat,
                        const float* __restrict__ col_compat,
                        float* __restrict__ g) {
    int tile = blockIdx.y;
    int e = blockIdx.x * blockDim.x + threadIdx.x;
    if (e >= NB*64) return;
    int pos = e & 63;
    int ij  = e >> 6;
    int tY = tile & 15, tX = (tile >> 4) & 15, b = tile >> 8;
    int X = tX*8 + (pos >> 3), Y = tY*8 + (pos & 7);
    int di = ij / KF - SPAN;
    int dj = ij % KF - SPAN;
    int Xn = X + di, Yn = Y + dj;
    float val = 0.f;
    if (Xn >= 0 && Xn < HP && Yn >= 0 && Yn < WP) {
        const float* cb = cf + (size_t)b*3*PLP;
        int o0 = X*WP + Y, o = Xn*WP + Yn;
        float d0 = cb[o]         - cb[o0];
        float d1 = cb[PLP + o]   - cb[PLP + o0];
        float d2 = cb[2*PLP + o] - cb[2*PLP + o0];
        float cd2 = d0*d0 + d1*d1 + d2*d2;
        float ps  = 4.f * pos_sdims[0];
        float pd2 = ps*ps * (float)(di*di + dj*dj);
        val = pos_compat[0] * expf(-0.5f*pd2) + col_compat[0] * expf(-0.5f*cd2);
    }
    g[(size_t)tile*NB*64 + e] = val;
}

// p0 = 4x4 pool of log_softmax(unary), packed fp32 [b][X][Y][24].
__global__ __launch_bounds__(256) void init_p_k(const float* __restrict__ unary,
                                                float* __restrict__ p) {
    int b = blockIdx.z, tx = blockIdx.y, ty = blockIdx.x;
    int t = threadIdx.x;
    int row = t >> 4, c2 = t & 15;
    int x = tx*16 + row, y = ty*32 + 2*c2;
    size_t base = (size_t)b*CC*PLF + (size_t)x*WW + y;
    float va[CC], vb[CC];
    float ma = -1e30f, mb = -1e30f;
    #pragma unroll
    for (int c = 0; c < CC; ++c) {
        float2 u = *(const float2*)(unary + base + (size_t)c*PLF);
        va[c] = u.x; vb[c] = u.y;
        ma = fmaxf(ma, u.x); mb = fmaxf(mb, u.y);
    }
    float sa = 0.f, sb = 0.f;
    #pragma unroll
    for (int c = 0; c < CC; ++c) { sa += expf(va[c]-ma); sb += expf(vb[c]-mb); }
    float lsa = ma + logf(sa), lsb = mb + logf(sb);
    float out[PC];
    #pragma unroll
    for (int c = 0; c < PC; ++c) out[c] = 0.f;
    #pragma unroll
    for (int c = 0; c < CC; ++c) {
        float sm = (va[c]-lsa) + (vb[c]-lsb);
        sm += __shfl_xor(sm, 1);
        sm += __shfl_xor(sm, 16);
        sm += __shfl_xor(sm, 32);
        out[c] = sm * (1.f/16.f);
    }
    int lane = t & 63;
    if ((lane & 49) == 0) {                  // bits {0,4,5} == 0
        int X = tx*4 + (t >> 6), Y = ty*8 + (c2 >> 1);
        float4* dst = (float4*)(p + ((size_t)(b*HP + X)*WP + Y)*PC);
        const float4* src = (const float4*)out;
        dst[0]=src[0]; dst[1]=src[1]; dst[2]=src[2];
        dst[3]=src[3]; dst[4]=src[4]; dst[5]=src[5];
    }
}

// msg[b,c,X,Y] = sum_ij g[b,ij,X,Y] * p_packed[b,X+di-5,Y+dj-5,c]
// 256 thr = 4 waves, channel-major; wave w owns di rows {0-2,3-5,6-8,9-10}
// (wave 3's third row is row 10 with a x0 mask -> exact). g prefetched to
// registers before staging; partials reduced through stride-25 LDS.
__global__ __launch_bounds__(256) void msg_k(const float* __restrict__ g,
                                             const float* __restrict__ p,
                                             float* __restrict__ msg) {
    int b = blockIdx.z, tx = blockIdx.y, ty = blockIdx.x;
    int t = threadIdx.x;
    __shared__ __align__(16) float pt[18*18*LSTR];     // 36.3 KB
    __shared__ float rbuf[3][64][RSTR];                // 19.2 KB
    int w = t >> 6, lane = t & 63;

    // ---- g prefetch (33 coalesced 256B loads, issued before staging so
    //      their latency hides under the halo stage + barrier) ----
    const float* gt = g + (size_t)((b*16 + tx)*16 + ty)*NB*64 + lane;
    int row0 = w*3, row1 = w*3 + 1;
    int row2 = (w == 3) ? 10 : w*3 + 2;
    float gm = (w == 3) ? 0.f : 1.f;
    float gvals[33];
    #pragma unroll
    for (int dj = 0; dj < KF; ++dj)
        gvals[dj]      = gt[(size_t)(row0*KF + dj) * 64];
    #pragma unroll
    for (int dj = 0; dj < KF; ++dj)
        gvals[11 + dj] = gt[(size_t)(row1*KF + dj) * 64];
    #pragma unroll
    for (int dj = 0; dj < KF; ++dj)
        gvals[22 + dj] = gt[(size_t)(row2*KF + dj) * 64] * gm;

    // ---- stage p halo ----
    int X0 = tx*8 - SPAN, Y0 = ty*8 - SPAN;
    const float4* pg = (const float4*)(p + (size_t)b*PLP*PC);
    for (int e = t; e < 18*18*6; e += 256) {
        int pos = e / 6, k = e % 6;
        int r = pos / 18, cl = pos % 18;
        int gX = X0 + r, gY = Y0 + cl;
        float4 v = {0.f,0.f,0.f,0.f};
        if (gX >= 0 && gX < HP && gY >= 0 && gY < WP)
            v = pg[(size_t)(gX*WP + gY)*6 + k];
        *(float4*)(pt + pos*LSTR + k*4) = v;
    }
    __syncthreads();

    int x = lane >> 3, y = lane & 7;
    int rows[3] = {row0, row1, row2};
    float acc[CC];
    #pragma unroll
    for (int c = 0; c < CC; ++c) acc[c] = 0.f;
    #pragma unroll
    for (int r = 0; r < 3; ++r) {
        const float* prow = pt + ((x + rows[r])*18 + y)*LSTR;
        #pragma unroll
        for (int dj = 0; dj < KF; ++dj) {
            float gv = gvals[r*11 + dj];
            const float4* sp = (const float4*)(prow + dj*LSTR);
            float4 q0 = sp[0], q1 = sp[1], q2 = sp[2];
            float4 q3 = sp[3], q4 = sp[4], q5 = sp[5];
            acc[0]  = fmaf(gv, q0.x, acc[0]);  acc[1]  = fmaf(gv, q0.y, acc[1]);
            acc[2]  = fmaf(gv, q0.z, acc[2]);  acc[3]  = fmaf(gv, q0.w, acc[3]);
            acc[4]  = fmaf(gv, q1.x, acc[4]);  acc[5]  = fmaf(gv, q1.y, acc[5]);
            acc[6]  = fmaf(gv, q1.z, acc[6]);  acc[7]  = fmaf(gv, q1.w, acc[7]);
            acc[8]  = fmaf(gv, q2.x, acc[8]);  acc[9]  = fmaf(gv, q2.y, acc[9]);
            acc[10] = fmaf(gv, q2.z, acc[10]); acc[11] = fmaf(gv, q2.w, acc[11]);
            acc[12] = fmaf(gv, q3.x, acc[12]); acc[13] = fmaf(gv, q3.y, acc[13]);
            acc[14] = fmaf(gv, q3.z, acc[14]); acc[15] = fmaf(gv, q3.w, acc[15]);
            acc[16] = fmaf(gv, q4.x, acc[16]); acc[17] = fmaf(gv, q4.y, acc[17]);
            acc[18] = fmaf(gv, q4.z, acc[18]); acc[19] = fmaf(gv, q4.w, acc[19]);
            acc[20] = fmaf(gv, q5.x, acc[20]);
        }
    }
    if (w > 0) {
        #pragma unroll
        for (int c = 0; c < CC; ++c) rbuf[w-1][lane][c] = acc[c];
    }
    __syncthreads();
    if (w == 0) {
        int Xg = tx*8 + x, Yg = ty*8 + y;
        float* mb = msg + (size_t)b*CC*PLP + (size_t)Xg*WP + Yg;
        #pragma unroll
        for (int c = 0; c < CC; ++c) {
            float s = ((acc[c] + rbuf[0][lane][c]) + rbuf[1][lane][c])
                      + rbuf[2][lane][c];
            mb[(size_t)c*PLP] = s;
        }
    }
}

// bilinear 4x upsample of msg + 0.8*lg + 0.2*mu; iters 0..3: softmax + 4x4
// pool -> packed p; last iter: write fp32 pred. 2 pixels per thread.
__global__ __launch_bounds__(256) void combine_k(const float* __restrict__ msg,
                                                 const float* __restrict__ unary,
                                                 const float* __restrict__ weight,
                                                 float* __restrict__ pnew,
                                                 float* __restrict__ pred,
                                                 int last) {
    int b = blockIdx.z, tx = blockIdx.y, ty = blockIdx.x;
    int t = threadIdx.x;
    __shared__ float ms[CC][6][10];
    const float* mb = msg + (size_t)b*CC*PLP;
    for (int e = t; e < CC*60; e += 256) {
        int c = e / 60, rr = (e / 10) % 6, cl = e % 10;
        int gX = tx*4 - 1 + rr; gX = gX < 0 ? 0 : (gX > HP-1 ? HP-1 : gX);
        int gY = ty*8 - 1 + cl; gY = gY < 0 ? 0 : (gY > WP-1 ? WP-1 : gY);
        ms[c][rr][cl] = mb[(size_t)c*PLP + gX*WP + gY];
    }
    __syncthreads();
    int row = t >> 4, c2 = t & 15;
    int x = tx*16 + row, y = ty*32 + 2*c2;
    size_t base = (size_t)b*CC*PLF + (size_t)x*WW + y;
    // bilinear: fx per (x%4): {0.625, 0.875, 0.125, 0.375}
    int rs = row & 3, q = row >> 2;
    float fx = (rs == 0) ? 0.625f : (rs == 1) ? 0.875f : (rs == 2) ? 0.125f : 0.375f;
    int i0 = q + (rs >> 1);
    int cs0 = (2*c2) & 3;                    // 0 or 2; pixel pair shares j0
    int qc  = (2*c2) >> 2;
    float fya = (cs0 == 0) ? 0.625f : 0.125f;
    float fyb = (cs0 == 0) ? 0.875f : 0.375f;
    int j0 = qc + (cs0 >> 1);
    float gx0 = 1.f - fx;
    float wt = weight[0], uw = 1.f - wt;     // UNARY_WEIGHT = 1.0
    float va[CC], vb[CC];
    float ma = -1e30f, mbx = -1e30f;
    #pragma unroll
    for (int c = 0; c < CC; ++c) {
        float2 u = *(const float2*)(unary + base + (size_t)c*PLF);
        va[c] = u.x; vb[c] = u.y;
        ma = fmaxf(ma, u.x); mbx = fmaxf(mbx, u.y);
    }
    float sa = 0.f, sb = 0.f;
    #pragma unroll
    for (int c = 0; c < CC; ++c) { sa += expf(va[c]-ma); sb += expf(vb[c]-mbx); }
    float lsa = ma + logf(sa), lsb = mbx + logf(sb);
    #pragma unroll
    for (int c = 0; c < CC; ++c) {
        float m00 = ms[c][i0][j0],   m01 = ms[c][i0][j0+1];
        float m10 = ms[c][i0+1][j0], m11 = ms[c][i0+1][j0+1];
        float ca = gx0*m00 + fx*m10;         // column j0 blended in x
        float cb = gx0*m01 + fx*m11;         // column j0+1 blended in x
        float mua = (1.f-fya)*ca + fya*cb;
        float mub = (1.f-fyb)*ca + fyb*cb;
        va[c] = uw*(va[c]-lsa) + wt*mua;
        vb[c] = uw*(vb[c]-lsb) + wt*mub;
    }
    if (last) {
        #pragma unroll
        for (int c = 0; c < CC; ++c) {
            float2 o; o.x = va[c]; o.y = vb[c];
            *(float2*)(pred + base + (size_t)c*PLF) = o;
        }
    } else {
        float mma = -1e30f, mmb = -1e30f;
        #pragma unroll
        for (int c = 0; c < CC; ++c) { mma = fmaxf(mma, va[c]); mmb = fmaxf(mmb, vb[c]); }
        float ssa = 0.f, ssb = 0.f;
        #pragma unroll
        for (int c = 0; c < CC; ++c) {
            va[c] = expf(va[c]-mma); ssa += va[c];
            vb[c] = expf(vb[c]-mmb); ssb += vb[c];
        }
        float ia = 1.f/ssa, ib = 1.f/ssb;
        float out[PC];
        #pragma unroll
        for (int c = 0; c < PC; ++c) out[c] = 0.f;
        #pragma unroll
        for (int c = 0; c < CC; ++c) {
            float sm = va[c]*ia + vb[c]*ib;
            sm += __shfl_xor(sm, 1);
            sm += __shfl_xor(sm, 16);
            sm += __shfl_xor(sm, 32);
            out[c] = sm * (1.f/16.f);
        }
        int lane = t & 63;
        if ((lane & 49) == 0) {
            int X = tx*4 + (t >> 6), Y = ty*8 + (c2 >> 1);
            float4* dst = (float4*)(pnew + ((size_t)(b*HP + X)*WP + Y)*PC);
            const float4* src = (const float4*)out;
            dst[0]=src[0]; dst[1]=src[1]; dst[2]=src[2];
            dst[3]=src[3]; dst[4]=src[4]; dst[5]=src[5];
        }
    }
}

extern "C" void kernel_launch(void* const* d_in, const int* in_sizes, int n_in,
                              void* d_out, int out_size, void* d_ws, size_t ws_size,
                              hipStream_t stream) {
    const float* unary      = (const float*)d_in[0];
    const float* img        = (const float*)d_in[1];
    const float* pos_sdims  = (const float*)d_in[2];
    const float* col_schan  = (const float*)d_in[3];
    const float* pos_compat = (const float*)d_in[4];
    const float* col_compat = (const float*)d_in[5];
    const float* weight     = (const float*)d_in[6];
    float* pred = (float*)d_out;
    float* ws   = (float*)d_ws;

    size_t o = 0;
    float* cf  = ws + o;  o += (size_t)BB*3*PLP;     // 0.4 MB
    float* g   = ws + o;  o += (size_t)BB*NB*PLP;    // 15.9 MB (tiled)
    float* msg = ws + o;  o += (size_t)BB*CC*PLP;    // 2.75 MB
    float* pA  = ws + o;  o += (size_t)BB*PLP*PC;    // 3.1 MB packed
    float* pB  = ws + o;
    float* pbuf[2] = {pA, pB};

    const int TB = 256;
    hipLaunchKernelGGL(pool_img_k, dim3((BB*3*PLP+TB-1)/TB), dim3(TB), 0, stream,
                       img, col_schan, cf);
    hipLaunchKernelGGL(gauss_k, dim3((NB*64+TB-1)/TB, 512), dim3(TB), 0, stream,
                       cf, pos_sdims, pos_compat, col_compat, g);
    hipLaunchKernelGGL(init_p_k, dim3(16, 32, BB), dim3(256), 0, stream,
                       unary, pA);
    for (int it = 0; it < NITER; ++it) {
        hipLaunchKernelGGL(msg_k, dim3(16, 16, BB), dim3(256), 0, stream,
                           g, pbuf[it & 1], msg);
        hipLaunchKernelGGL(combine_k, dim3(16, 32, BB), dim3(256), 0, stream,
                           msg, unary, weight, pbuf[(it + 1) & 1],
                           pred, (it == NITER-1) ? 1 : 0);
    }
}